// Round 1
// baseline (28209.012 us; speedup 1.0000x reference)
//
#include <hip/hip_runtime.h>

typedef unsigned int u32;
typedef unsigned short u16;
typedef _Float16 h2t __attribute__((ext_vector_type(2)));

union H2U { u32 u; h2t h; u16 s[2]; };

#if defined(__has_builtin)
#if __has_builtin(__builtin_amdgcn_fdot2)
#define HAS_FDOT2 1
#endif
#endif

__device__ __forceinline__ float dot2f(u32 w, u32 x, float acc){
  H2U a, b; a.u = w; b.u = x;
#ifdef HAS_FDOT2
  return __builtin_amdgcn_fdot2(a.h, b.h, acc, false);
#else
  return acc + (float)a.h.x * (float)b.h.x + (float)a.h.y * (float)b.h.y;
#endif
}

__device__ __forceinline__ u32 packh2(float a, float b){
  H2U u; u.h.x = (_Float16)a; u.h.y = (_Float16)b; return u.u;
}
__device__ __forceinline__ u16 f16b(float x){
  union { _Float16 h; u16 u; } c; c.h = (_Float16)x; return c.u;
}
__device__ __forceinline__ float sigm(float x){ return 1.0f/(1.0f + __expf(-x)); }

// ---------------------------------------------------------------------------
// Weight repack: transpose to k-major, convert to f16, pack 4 k's per uint2
// so the GRU kernel's loads are fully coalesced dwordx2 across 512 threads.
//   whh_p: [3][128][512] uint2   (gate, k/4, j)   1,572,864 B
//   wih_p: [3][ 32][512] uint2                      393,216 B
//   wfc_p: [8][ 16][ 64] uint2   (kslice, k4, i)     65,536 B
// ---------------------------------------------------------------------------
#define NHH (3*128*512)
#define NIH (3*32*512)
#define NFC (8*16*64)

__global__ __launch_bounds__(256) void prep_kernel(
    const float* __restrict__ W_ih, const float* __restrict__ W_hh,
    const float* __restrict__ fc_W, uint2* __restrict__ whh_p,
    uint2* __restrict__ wih_p, uint2* __restrict__ wfc_p){
  int idx = blockIdx.x*256 + threadIdx.x;
  if (idx < NHH){
    int g = idx >> 16, rem = idx & 65535, k4 = rem >> 9, jj = rem & 511;
    const float* src = W_hh + (g*512 + jj)*512 + k4*4;
    whh_p[idx] = make_uint2(packh2(src[0],src[1]), packh2(src[2],src[3]));
  } else if (idx < NHH + NIH){
    int t = idx - NHH;
    int g = t >> 14, rem = t & 16383, k4 = rem >> 9, jj = rem & 511;
    const float* src = W_ih + (g*512 + jj)*128 + k4*4;
    wih_p[t] = make_uint2(packh2(src[0],src[1]), packh2(src[2],src[3]));
  } else {
    int t = idx - NHH - NIH;
    int ss = t >> 10, rem = t & 1023, k4 = rem >> 6, i = rem & 63;
    const float* src = fc_W + i*512 + ss*64 + k4*4;
    wfc_p[t] = make_uint2(packh2(src[0],src[1]), packh2(src[2],src[3]));
  }
}

// ---------------------------------------------------------------------------
// X_prior: one WG (1 wave) per batch. x_new[i] = sum_j F[i][j] * x[j].
// Lane i holds F row i in 64 VGPRs; x broadcast via LDS, double-buffered.
// Writes X_prior into d_out (final kernel adds dX in place).
// ---------------------------------------------------------------------------
__global__ __launch_bounds__(64) void xprior_kernel(
    const float* __restrict__ F, const float* __restrict__ x0,
    float* __restrict__ out){
  int b = blockIdx.x, i = threadIdx.x;
  __shared__ float xb[2][64];
  float f[64];
  #pragma unroll
  for (int j=0;j<64;j++) f[j] = F[i*64+j];
  xb[0][i] = x0[b*64+i];
  __syncthreads();
  float* o = out + b*1024*64;
  for (int t=0;t<1024;t++){
    int cur = t & 1;
    float a0=0.f,a1=0.f,a2=0.f,a3=0.f;
    #pragma unroll
    for (int j=0;j<64;j+=4){
      a0 = fmaf(f[j+0], xb[cur][j+0], a0);
      a1 = fmaf(f[j+1], xb[cur][j+1], a1);
      a2 = fmaf(f[j+2], xb[cur][j+2], a2);
      a3 = fmaf(f[j+3], xb[cur][j+3], a3);
    }
    float a = (a0+a1)+(a2+a3);
    o[t*64+i] = a;
    xb[cur^1][i] = a;
    __syncthreads();
  }
}

// ---------------------------------------------------------------------------
// Fused GRU + input-proj + fc: one WG (512 thr) per batch. Thread j owns
// gate rows {j, 512+j, 1024+j} -> computes h_new[j] with no cross-thread
// reduction. h carry stays f32 in a register; dot inputs are f16 via LDS.
// Weights stream from L2 every step (round-0 structural limit ~3.7 ms).
// ---------------------------------------------------------------------------
__global__ __launch_bounds__(512) void gru_kernel(
    const float* __restrict__ Y, const float* __restrict__ b_ih,
    const float* __restrict__ b_hh, const float* __restrict__ fc_b,
    const uint2* __restrict__ WIH, const uint2* __restrict__ WHH,
    const uint2* __restrict__ WFC, float* __restrict__ out){
  int b = blockIdx.x, j = threadIdx.x;
  int ss = j >> 6, ii = j & 63;
  __shared__ u32 inp2[64];        // [Y(t) , X_prior(t)] as 64x half2
  __shared__ float xp_lds[64];    // X_prior(t) in f32 for the final add
  __shared__ u32 hbuf2[256];      // h state as 256x half2
  __shared__ float fcred[8][64];  // fc partial sums
  float br  = b_ih[j]      + b_hh[j];
  float bz  = b_ih[512+j]  + b_hh[512+j];
  float bxn = b_ih[1024+j];
  float bhn = b_hh[1024+j];
  float fb  = (j<64)? fc_b[j] : 0.f;
  float hreg = 0.f;
  if (j < 256) hbuf2[j] = 0u;
  const float* yb = Y   + b*1024*64;
  float*       ob = out + b*1024*64;
  for (int t=0;t<1024;t++){
    const float* yrow = yb + t*64;
    float*       orow = ob + t*64;
    if (j < 64){
      xp_lds[j] = orow[j];
      if (j < 32){
        float2 v = *(const float2*)(yrow + 2*j);
        inp2[j] = packh2(v.x, v.y);
      } else {
        float2 v = *(const float2*)(orow + 2*(j-32));
        inp2[j] = packh2(v.x, v.y);
      }
    }
    __syncthreads(); // B1: inputs staged, hbuf2 holds h_t
    float sr=br, sz=bz, sxn=bxn, shn=bhn;
    #pragma unroll 8
    for (int m=0;m<32;m++){
      uint2 wr = WIH[(m   )*512 + j];
      uint2 wz = WIH[(32+m)*512 + j];
      uint2 wn = WIH[(64+m)*512 + j];
      u32 x0 = inp2[2*m], x1 = inp2[2*m+1];
      sr  = dot2f(wr.x,x0,sr );  sr  = dot2f(wr.y,x1,sr );
      sz  = dot2f(wz.x,x0,sz );  sz  = dot2f(wz.y,x1,sz );
      sxn = dot2f(wn.x,x0,sxn);  sxn = dot2f(wn.y,x1,sxn);
    }
    #pragma unroll 8
    for (int m=0;m<128;m++){
      uint2 wr = WHH[(m     )*512 + j];
      uint2 wz = WHH[(128+m)*512 + j];
      uint2 wn = WHH[(256+m)*512 + j];
      u32 h0 = hbuf2[2*m], h1 = hbuf2[2*m+1];
      sr  = dot2f(wr.x,h0,sr );  sr  = dot2f(wr.y,h1,sr );
      sz  = dot2f(wz.x,h0,sz );  sz  = dot2f(wz.y,h1,sz );
      shn = dot2f(wn.x,h0,shn);  shn = dot2f(wn.y,h1,shn);
    }
    float r  = sigm(sr);
    float zg = sigm(sz);
    float ng = tanhf(sxn + r*shn);
    float hnew = (1.f - zg)*ng + zg*hreg;
    hreg = hnew;
    __syncthreads(); // B2: all reads of h_t done
    ((u16*)hbuf2)[j] = f16b(hnew);
    __syncthreads(); // B3: hbuf2 = h_{t+1}
    float p = 0.f;
    #pragma unroll
    for (int k4=0;k4<16;k4++){
      uint2 w = WFC[(ss*16 + k4)*64 + ii];
      u32 h0 = hbuf2[ss*32 + 2*k4], h1 = hbuf2[ss*32 + 2*k4 + 1];
      p = dot2f(w.x,h0,p);  p = dot2f(w.y,h1,p);
    }
    fcred[ss][ii] = p;
    __syncthreads(); // B4
    if (j < 64){
      float dx = fb + xp_lds[j];
      #pragma unroll
      for (int q=0;q<8;q++) dx += fcred[q][j];
      orow[j] = dx;  // out = X_prior + dX
    }
  }
}

extern "C" void kernel_launch(void* const* d_in, const int* in_sizes, int n_in,
                              void* d_out, int out_size, void* d_ws, size_t ws_size,
                              hipStream_t stream){
  (void)in_sizes; (void)n_in; (void)out_size; (void)ws_size;
  const float* Y   = (const float*)d_in[0];
  const float* x0  = (const float*)d_in[1];
  const float* F   = (const float*)d_in[2];
  const float* Wih = (const float*)d_in[3];
  const float* Whh = (const float*)d_in[4];
  const float* bih = (const float*)d_in[5];
  const float* bhh = (const float*)d_in[6];
  const float* fcW = (const float*)d_in[7];
  const float* fcb = (const float*)d_in[8];
  float* out = (float*)d_out;

  uint2* whh_p = (uint2*)d_ws;                          // 1,572,864 B
  uint2* wih_p = (uint2*)((char*)d_ws + 1572864);       //   393,216 B
  uint2* wfc_p = (uint2*)((char*)d_ws + 1966080);       //    65,536 B

  prep_kernel  <<<992, 256, 0, stream>>>(Wih, Whh, fcW, whh_p, wih_p, wfc_p);
  xprior_kernel<<< 64,  64, 0, stream>>>(F, x0, out);
  gru_kernel   <<< 64, 512, 0, stream>>>(Y, bih, bhh, fcb, wih_p, whh_p, wfc_p, out);
}

// Round 2
// 22744.751 us; speedup vs baseline: 1.2402x; 1.2402x over previous
//
#include <hip/hip_runtime.h>

typedef _Float16 half8 __attribute__((ext_vector_type(8)));
typedef float f32x4 __attribute__((ext_vector_type(4)));
typedef unsigned int u32;
typedef unsigned short u16;
typedef _Float16 h2t __attribute__((ext_vector_type(2)));

union H2U { u32 u; h2t h; u16 s[2]; };

#if defined(__has_builtin)
#if __has_builtin(__builtin_amdgcn_fdot2)
#define HAS_FDOT2 1
#endif
#endif

__device__ __forceinline__ float dot2f(u32 w, u32 x, float acc){
  H2U a, b; a.u = w; b.u = x;
#ifdef HAS_FDOT2
  return __builtin_amdgcn_fdot2(a.h, b.h, acc, false);
#else
  return acc + (float)a.h.x * (float)b.h.x + (float)a.h.y * (float)b.h.y;
#endif
}
__device__ __forceinline__ u32 packh2(float a, float b){
  H2U u; u.h.x = (_Float16)a; u.h.y = (_Float16)b; return u.u;
}
__device__ __forceinline__ u16 f16b(float x){
  union { _Float16 h; u16 u; } c; c.h = (_Float16)x; return c.u;
}
__device__ __forceinline__ float sigm(float x){ return 1.0f/(1.0f + __expf(-x)); }
__device__ __forceinline__ half8 pack8(float4 u, float4 v){
  half8 r;
  r[0]=(_Float16)u.x; r[1]=(_Float16)u.y; r[2]=(_Float16)u.z; r[3]=(_Float16)u.w;
  r[4]=(_Float16)v.x; r[5]=(_Float16)v.y; r[6]=(_Float16)v.z; r[7]=(_Float16)v.w;
  return r;
}

#define T_STEPS 1024
#define NB 64
#define HID 512
#define G3 1536
#define NOBS 64
#define MST 64
#define KIN 128

// ---- ws layout (persistent path), bytes ----
#define OFF_WHHK 0
#define SZ_WHHK (G3*HID*2)                    // 1,572,864
#define OFF_WIHK (OFF_WHHK + SZ_WHHK)
#define SZ_WIHK (G3*KIN*2)                    //   393,216
#define OFF_FCK (OFF_WIHK + SZ_WIHK)
#define SZ_FCK (MST*HID*2)                    //    65,536
#define OFF_HST (OFF_FCK + SZ_FCK)
#define SZ_HST (8*2*16*HID*2)                 //   262,144 (8 teams x 2 bufs x 16 rows x 512 f16)
#define OFF_FLG (OFF_HST + SZ_HST)
#define SZ_FLG (8*32*4)                       //     1,024
#define OFF_HFULL (OFF_FLG + SZ_FLG + 2048)   // aligned region
#define SZ_HFULL ((size_t)T_STEPS*NB*HID*2)   // 67,108,864
#define WS_NEED (OFF_HFULL + SZ_HFULL)

// ---------------------------------------------------------------------------
// prep2: f32->f16 weight conversion (layouts already k-contiguous) + zero
// hstate (both buffers, incl. padding rows 8..15) + zero team flags.
// ---------------------------------------------------------------------------
__global__ __launch_bounds__(256) void prep2_kernel(
    const float* __restrict__ W_ih, const float* __restrict__ W_hh,
    const float* __restrict__ fc_W, char* __restrict__ ws){
  _Float16* whhk = (_Float16*)(ws + OFF_WHHK);
  _Float16* wihk = (_Float16*)(ws + OFF_WIHK);
  _Float16* fck  = (_Float16*)(ws + OFF_FCK);
  u32* hz        = (u32*)(ws + OFF_HST);
  u32* flg       = (u32*)(ws + OFF_FLG);
  long idx = (long)blockIdx.x*256 + threadIdx.x;
  const long N1 = (long)G3*HID, N2 = (long)G3*KIN, N3 = (long)MST*HID;
  const long N4 = SZ_HST/4, N5 = 256;
  if (idx < N1) whhk[idx] = (_Float16)W_hh[idx];
  else if (idx < N1+N2) wihk[idx-N1] = (_Float16)W_ih[idx-N1];
  else if (idx < N1+N2+N3) fck[idx-N1-N2] = (_Float16)fc_W[idx-N1-N2];
  else if (idx < N1+N2+N3+N4) hz[idx-N1-N2-N3] = 0u;
  else if (idx < N1+N2+N3+N4+N5) flg[idx-N1-N2-N3-N4] = 0u;
}

// ---------------------------------------------------------------------------
// X_prior: one WG (1 wave) per batch; F row-resident in VGPRs.
// Writes X_prior into d_out (fc kernel later adds dX in place).
// ---------------------------------------------------------------------------
__global__ __launch_bounds__(64) void xprior_kernel(
    const float* __restrict__ F, const float* __restrict__ x0,
    float* __restrict__ out){
  int b = blockIdx.x, i = threadIdx.x;
  __shared__ float xb[2][64];
  float f[64];
  #pragma unroll
  for (int j=0;j<64;j++) f[j] = F[i*64+j];
  xb[0][i] = x0[b*64+i];
  __syncthreads();
  float* o = out + (size_t)b*1024*64;
  for (int t=0;t<1024;t++){
    int cur = t & 1;
    float a0=0.f,a1=0.f,a2=0.f,a3=0.f;
    #pragma unroll
    for (int j=0;j<64;j+=4){
      a0 = fmaf(f[j+0], xb[cur][j+0], a0);
      a1 = fmaf(f[j+1], xb[cur][j+1], a1);
      a2 = fmaf(f[j+2], xb[cur][j+2], a2);
      a3 = fmaf(f[j+3], xb[cur][j+3], a3);
    }
    float a = (a0+a1)+(a2+a3);
    o[t*64+i] = a;
    xb[cur^1][i] = a;
    __syncthreads();
  }
}

// ---------------------------------------------------------------------------
// Persistent GRU. 256 WGs x 192 thr. Team g = {blk : blk%8==g} (XCD-local
// under round-robin placement; correctness placement-independent). Member
// m = blk/8 owns hidden units j in [m*16,(m+1)*16) for the team's 8 batches.
// Wave wv in {0,1,2} = gate {r,z,n}. W_hh/W_ih fragments live in VGPRs for
// the whole run. h exchanged via double-buffered hstate + flag-array
// release/acquire (agent scope). MFMA 16x16x32 f16, M=16 (8 real batches).
// ---------------------------------------------------------------------------
__global__ __launch_bounds__(192, 1) void gru_pers(
    const float* __restrict__ Y, const float* __restrict__ Xp,
    const float* __restrict__ b_ih, const float* __restrict__ b_hh,
    char* __restrict__ ws){
  const _Float16* whhk = (const _Float16*)(ws + OFF_WHHK);
  const _Float16* wihk = (const _Float16*)(ws + OFF_WIHK);
  _Float16* hstate     = (_Float16*)(ws + OFF_HST);
  u32* flags           = (u32*)(ws + OFF_FLG);
  _Float16* h_full     = (_Float16*)(ws + OFF_HFULL);

  const int w = blockIdx.x, g = w & 7, m = w >> 3;
  const int tid = threadIdx.x, wv = tid >> 6, lane = tid & 63;
  const int lr = lane & 15, lk = lane >> 4;

  // Persistent B fragments: B[k][n] = W[row n][k]; lane holds col n=lr,
  // k = c*32 + lk*8 + i. Rows for this (wave, member): wv*512 + m*16 + lr.
  const int grow = wv*512 + m*16 + lr;
  half8 Bh[16], Bx[4];
  #pragma unroll
  for (int c=0;c<16;c++)
    Bh[c] = *(const half8*)(whhk + (size_t)grow*HID + c*32 + lk*8);
  #pragma unroll
  for (int c=0;c<4;c++)
    Bx[c] = *(const half8*)(wihk + (size_t)grow*KIN + c*32 + lk*8);

  // Gate-phase constants (threads 0..127: thread = b*16 + jj)
  const int gb = tid >> 4, gj = tid & 15;
  const int jg = m*16 + gj;
  const float b_r  = b_ih[jg]       + b_hh[jg];
  const float b_z  = b_ih[512+jg]   + b_hh[512+jg];
  const float b_nx = b_ih[1024+jg];
  const float b_nh = b_hh[1024+jg];
  float hold = 0.f;

  const int bclamp = (lr < 8) ? lr : 7;   // pad rows read b=7 (results unused)
  const float* Yb  = Y  + (size_t)(g*8 + bclamp)*T_STEPS*NOBS;
  const float* Xpb = Xp + (size_t)(g*8 + bclamp)*T_STEPS*MST;

  _Float16* hsg = hstate + (size_t)g*(2*16*HID);
  u32* flg = flags + g*32;
  const int pollIdx = tid & 31;

  __shared__ float Cg[4][8][16];   // r, z, n_hh, n_ih

  for (int t=0;t<T_STEPS;t++){
    // 1) inp loads for step t — independent of flags, issued before poll
    const float* ysrc = Yb  + (size_t)t*NOBS;
    const float* xsrc = Xpb + (size_t)t*MST;
    float4 ya0 = *(const float4*)(ysrc + lk*8);
    float4 ya1 = *(const float4*)(ysrc + lk*8 + 4);
    float4 yb0 = *(const float4*)(ysrc + 32 + lk*8);
    float4 yb1 = *(const float4*)(ysrc + 32 + lk*8 + 4);
    float4 xa0 = *(const float4*)(xsrc + lk*8);
    float4 xa1 = *(const float4*)(xsrc + lk*8 + 4);
    float4 xb0 = *(const float4*)(xsrc + 32 + lk*8);
    float4 xb1 = *(const float4*)(xsrc + 32 + lk*8 + 4);

    // 2) wait for h_t to be visible (flags[*] >= t)
    for(;;){
      u32 v = __hip_atomic_load(&flg[pollIdx], __ATOMIC_ACQUIRE, __HIP_MEMORY_SCOPE_AGENT);
      if (__syncthreads_and((int)(v >= (u32)t))) break;
      __builtin_amdgcn_s_sleep(1);
    }

    // 3) MFMA: Cx = W_ih·inp (4 chunks), Ch = W_hh·h (16 chunks)
    f32x4 Ch = {0.f,0.f,0.f,0.f};
    f32x4 Cx = {0.f,0.f,0.f,0.f};
    {
      half8 Ax0 = pack8(ya0, ya1), Ax1 = pack8(yb0, yb1);
      half8 Ax2 = pack8(xa0, xa1), Ax3 = pack8(xb0, xb1);
      Cx = __builtin_amdgcn_mfma_f32_16x16x32_f16(Ax0, Bx[0], Cx, 0,0,0);
      Cx = __builtin_amdgcn_mfma_f32_16x16x32_f16(Ax1, Bx[1], Cx, 0,0,0);
      Cx = __builtin_amdgcn_mfma_f32_16x16x32_f16(Ax2, Bx[2], Cx, 0,0,0);
      Cx = __builtin_amdgcn_mfma_f32_16x16x32_f16(Ax3, Bx[3], Cx, 0,0,0);
    }
    const _Float16* hb = hsg + (t&1)*(16*HID) + lr*HID + lk*8;
    #pragma unroll
    for (int c=0;c<16;c++){
      half8 Ah = *(const half8*)(hb + c*32);
      Ch = __builtin_amdgcn_mfma_f32_16x16x32_f16(Ah, Bh[c], Ch, 0,0,0);
    }

    // 4) stage valid C rows (m<8 -> lanes with lk<2) to LDS
    if (lk < 2){
      #pragma unroll
      for (int r=0;r<4;r++){
        int mb = lk*4 + r;
        if (wv == 2){ Cg[2][mb][lr] = Ch[r]; Cg[3][mb][lr] = Cx[r]; }
        else          Cg[wv][mb][lr] = Ch[r] + Cx[r];
      }
    }
    __syncthreads();

    // 5) gates + state update (threads 0..127)
    if (tid < 128){
      float cr  = Cg[0][gb][gj] + b_r;
      float cz  = Cg[1][gb][gj] + b_z;
      float cnh = Cg[2][gb][gj] + b_nh;
      float cnx = Cg[3][gb][gj] + b_nx;
      float r = sigm(cr);
      float z = sigm(cz);
      float n = tanhf(cnx + r*cnh);
      float hn = (1.f - z)*n + z*hold;
      hold = hn;
      _Float16 h16 = (_Float16)hn;
      hsg[((t+1)&1)*(16*HID) + gb*HID + jg] = h16;
      h_full[((size_t)t*NB + (g*8+gb))*HID + jg] = h16;
    }
    __syncthreads();   // drains each thread's stores before the release

    // 6) publish step completion
    if (tid == 0){
      __threadfence();
      __hip_atomic_store(&flg[m], (u32)(t+1), __ATOMIC_RELEASE, __HIP_MEMORY_SCOPE_AGENT);
    }
  }
}

// ---------------------------------------------------------------------------
// Deferred fc: out = X_prior(d_out) + h_full @ fcW^T + fc_b. MFMA, parallel.
// Grid: 64 b x 32 t-chunks; WG 256 thr; wave wv owns n-tile wv (N=64).
// ---------------------------------------------------------------------------
__global__ __launch_bounds__(256) void fc_kernel(
    const float* __restrict__ fc_b, const char* __restrict__ ws,
    float* __restrict__ out){
  const _Float16* fck    = (const _Float16*)(ws + OFF_FCK);
  const _Float16* h_full = (const _Float16*)(ws + OFF_HFULL);
  int blk = blockIdx.x;
  int b  = blk >> 5;
  int t0 = (blk & 31) * 32;
  int tid = threadIdx.x, wv = tid >> 6, lane = tid & 63;
  int lr = lane & 15, lk = lane >> 4;
  int n = wv*16 + lr;
  half8 Bf[16];
  #pragma unroll
  for (int c=0;c<16;c++)
    Bf[c] = *(const half8*)(fck + (size_t)n*HID + c*32 + lk*8);
  float bias = fc_b[n];
  #pragma unroll
  for (int mt=0;mt<2;mt++){
    f32x4 C = {0.f,0.f,0.f,0.f};
    #pragma unroll
    for (int c=0;c<16;c++){
      half8 A = *(const half8*)(h_full + ((size_t)(t0+mt*16+lr)*NB + b)*HID + c*32 + lk*8);
      C = __builtin_amdgcn_mfma_f32_16x16x32_f16(A, Bf[c], C, 0,0,0);
    }
    #pragma unroll
    for (int r=0;r<4;r++){
      int trow = t0 + mt*16 + lk*4 + r;
      size_t o = ((size_t)b*T_STEPS + trow)*MST + n;
      out[o] = out[o] + bias + C[r];
    }
  }
}

// ===========================================================================
// Fallback path (round-1 kernels) — used only if ws_size < WS_NEED.
// ===========================================================================
#define NHH (3*128*512)
#define NIH (3*32*512)
#define NFC (8*16*64)

__global__ __launch_bounds__(256) void prep_kernel(
    const float* __restrict__ W_ih, const float* __restrict__ W_hh,
    const float* __restrict__ fc_W, uint2* __restrict__ whh_p,
    uint2* __restrict__ wih_p, uint2* __restrict__ wfc_p){
  int idx = blockIdx.x*256 + threadIdx.x;
  if (idx < NHH){
    int g = idx >> 16, rem = idx & 65535, k4 = rem >> 9, jj = rem & 511;
    const float* src = W_hh + (g*512 + jj)*512 + k4*4;
    whh_p[idx] = make_uint2(packh2(src[0],src[1]), packh2(src[2],src[3]));
  } else if (idx < NHH + NIH){
    int t = idx - NHH;
    int g = t >> 14, rem = t & 16383, k4 = rem >> 9, jj = rem & 511;
    const float* src = W_ih + (g*512 + jj)*128 + k4*4;
    wih_p[t] = make_uint2(packh2(src[0],src[1]), packh2(src[2],src[3]));
  } else {
    int t = idx - NHH - NIH;
    int ss = t >> 10, rem = t & 1023, k4 = rem >> 6, i = rem & 63;
    const float* src = fc_W + i*512 + ss*64 + k4*4;
    wfc_p[t] = make_uint2(packh2(src[0],src[1]), packh2(src[2],src[3]));
  }
}

__global__ __launch_bounds__(512) void gru_kernel(
    const float* __restrict__ Y, const float* __restrict__ b_ih,
    const float* __restrict__ b_hh, const float* __restrict__ fc_b,
    const uint2* __restrict__ WIH, const uint2* __restrict__ WHH,
    const uint2* __restrict__ WFC, float* __restrict__ out){
  int b = blockIdx.x, j = threadIdx.x;
  int ss = j >> 6, ii = j & 63;
  __shared__ u32 inp2[64];
  __shared__ float xp_lds[64];
  __shared__ u32 hbuf2[256];
  __shared__ float fcred[8][64];
  float br  = b_ih[j]      + b_hh[j];
  float bz  = b_ih[512+j]  + b_hh[512+j];
  float bxn = b_ih[1024+j];
  float bhn = b_hh[1024+j];
  float fb  = (j<64)? fc_b[j] : 0.f;
  float hreg = 0.f;
  if (j < 256) hbuf2[j] = 0u;
  const float* yb = Y   + (size_t)b*1024*64;
  float*       ob = out + (size_t)b*1024*64;
  for (int t=0;t<1024;t++){
    const float* yrow = yb + t*64;
    float*       orow = ob + t*64;
    if (j < 64){
      xp_lds[j] = orow[j];
      if (j < 32){
        float2 v = *(const float2*)(yrow + 2*j);
        inp2[j] = packh2(v.x, v.y);
      } else {
        float2 v = *(const float2*)(orow + 2*(j-32));
        inp2[j] = packh2(v.x, v.y);
      }
    }
    __syncthreads();
    float sr=br, sz=bz, sxn=bxn, shn=bhn;
    #pragma unroll 8
    for (int m=0;m<32;m++){
      uint2 wr = WIH[(m   )*512 + j];
      uint2 wz = WIH[(32+m)*512 + j];
      uint2 wn = WIH[(64+m)*512 + j];
      u32 x0 = inp2[2*m], x1 = inp2[2*m+1];
      sr  = dot2f(wr.x,x0,sr );  sr  = dot2f(wr.y,x1,sr );
      sz  = dot2f(wz.x,x0,sz );  sz  = dot2f(wz.y,x1,sz );
      sxn = dot2f(wn.x,x0,sxn);  sxn = dot2f(wn.y,x1,sxn);
    }
    #pragma unroll 8
    for (int m=0;m<128;m++){
      uint2 wr = WHH[(m     )*512 + j];
      uint2 wz = WHH[(128+m)*512 + j];
      uint2 wn = WHH[(256+m)*512 + j];
      u32 h0 = hbuf2[2*m], h1 = hbuf2[2*m+1];
      sr  = dot2f(wr.x,h0,sr );  sr  = dot2f(wr.y,h1,sr );
      sz  = dot2f(wz.x,h0,sz );  sz  = dot2f(wz.y,h1,sz );
      shn = dot2f(wn.x,h0,shn);  shn = dot2f(wn.y,h1,shn);
    }
    float r  = sigm(sr);
    float zg = sigm(sz);
    float ng = tanhf(sxn + r*shn);
    float hnew = (1.f - zg)*ng + zg*hreg;
    hreg = hnew;
    __syncthreads();
    ((u16*)hbuf2)[j] = f16b(hnew);
    __syncthreads();
    float p = 0.f;
    #pragma unroll
    for (int k4=0;k4<16;k4++){
      uint2 w2 = WFC[(ss*16 + k4)*64 + ii];
      u32 h0 = hbuf2[ss*32 + 2*k4], h1 = hbuf2[ss*32 + 2*k4 + 1];
      p = dot2f(w2.x,h0,p);  p = dot2f(w2.y,h1,p);
    }
    fcred[ss][ii] = p;
    __syncthreads();
    if (j < 64){
      float dx = fb + xp_lds[j];
      #pragma unroll
      for (int q=0;q<8;q++) dx += fcred[q][j];
      orow[j] = dx;
    }
  }
}

extern "C" void kernel_launch(void* const* d_in, const int* in_sizes, int n_in,
                              void* d_out, int out_size, void* d_ws, size_t ws_size,
                              hipStream_t stream){
  (void)in_sizes; (void)n_in; (void)out_size;
  const float* Y   = (const float*)d_in[0];
  const float* x0  = (const float*)d_in[1];
  const float* F   = (const float*)d_in[2];
  const float* Wih = (const float*)d_in[3];
  const float* Whh = (const float*)d_in[4];
  const float* bih = (const float*)d_in[5];
  const float* bhh = (const float*)d_in[6];
  const float* fcW = (const float*)d_in[7];
  const float* fcb = (const float*)d_in[8];
  float* out = (float*)d_out;

  if (ws_size >= (size_t)WS_NEED){
    char* ws = (char*)d_ws;
    prep2_kernel <<<4225, 256, 0, stream>>>(Wih, Whh, fcW, ws);
    xprior_kernel<<<  64,  64, 0, stream>>>(F, x0, out);
    gru_pers     <<< 256, 192, 0, stream>>>(Y, out, bih, bhh, ws);
    fc_kernel    <<<2048, 256, 0, stream>>>(fcb, ws, out);
  } else {
    uint2* whh_p = (uint2*)d_ws;
    uint2* wih_p = (uint2*)((char*)d_ws + 1572864);
    uint2* wfc_p = (uint2*)((char*)d_ws + 1966080);
    prep_kernel  <<<992, 256, 0, stream>>>(Wih, Whh, fcW, whh_p, wih_p, wfc_p);
    xprior_kernel<<< 64,  64, 0, stream>>>(F, x0, out);
    gru_kernel   <<< 64, 512, 0, stream>>>(Y, bih, bhh, fcb, wih_p, whh_p, wfc_p, out);
  }
}

// Round 3
// 5046.606 us; speedup vs baseline: 5.5897x; 4.5069x over previous
//
#include <hip/hip_runtime.h>

typedef unsigned int u32;
typedef unsigned short u16;
typedef _Float16 half8 __attribute__((ext_vector_type(8)));
typedef float f32x4 __attribute__((ext_vector_type(4)));
typedef _Float16 h2t __attribute__((ext_vector_type(2)));

union H2U { u32 u; h2t h; u16 s[2]; };
union U128 { uint4 u; half8 h; };

#if defined(__has_builtin)
#if __has_builtin(__builtin_amdgcn_fdot2)
#define HAS_FDOT2 1
#endif
#endif

__device__ __forceinline__ float dot2f(u32 w, u32 x, float acc){
  H2U a, b; a.u = w; b.u = x;
#ifdef HAS_FDOT2
  return __builtin_amdgcn_fdot2(a.h, b.h, acc, false);
#else
  return acc + (float)a.h.x * (float)b.h.x + (float)a.h.y * (float)b.h.y;
#endif
}
__device__ __forceinline__ u32 packh2(float a, float b){
  H2U u; u.h.x = (_Float16)a; u.h.y = (_Float16)b; return u.u;
}
__device__ __forceinline__ u16 f16b(float x){
  union { _Float16 h; u16 u; } c; c.h = (_Float16)x; return c.u;
}
__device__ __forceinline__ float sigm(float x){ return 1.0f/(1.0f + __expf(-x)); }
__device__ __forceinline__ half8 pack8(float4 u, float4 v){
  half8 r;
  r[0]=(_Float16)u.x; r[1]=(_Float16)u.y; r[2]=(_Float16)u.z; r[3]=(_Float16)u.w;
  r[4]=(_Float16)v.x; r[5]=(_Float16)v.y; r[6]=(_Float16)v.z; r[7]=(_Float16)v.w;
  return r;
}

// Coherence-point (IF$) access macros: no buffer_inv / buffer_wbl2 ever.
#define LDX4_SC(dst, base, off) \
  asm volatile("global_load_dwordx4 %0, %1, off offset:" #off " sc0 sc1" \
               : "=v"(dst) : "v"(base) : "memory")
#define STSH_SC(base, off, val) \
  asm volatile("global_store_short %0, %1, off offset:" #off " sc0 sc1" \
               :: "v"(base), "v"(val) : "memory")
#define STDW_SC(base, val) \
  asm volatile("global_store_dword %0, %1, off sc0 sc1" \
               :: "v"(base), "v"(val) : "memory")
#define WAIT_VM0() asm volatile("s_waitcnt vmcnt(0)" ::: "memory")

#define T_STEPS 1024
#define NB 64
#define HID 512
#define G3 1536
#define NOBS 64
#define MST 64
#define KIN 128
#define NTEAMS 4
#define NMEMB 16

// ---- ws layout (persistent path), bytes ----
#define OFF_WHHK 0
#define SZ_WHHK (G3*HID*2)                    // 1,572,864
#define OFF_WIHK (OFF_WHHK + SZ_WHHK)
#define SZ_WIHK (G3*KIN*2)                    //   393,216
#define OFF_FCK (OFF_WIHK + SZ_WIHK)
#define SZ_FCK (MST*HID*2)                    //    65,536
#define OFF_HST (OFF_FCK + SZ_FCK)
#define SZ_HST (NTEAMS*2*16*HID*2)            //   131,072
#define OFF_FLG (OFF_HST + SZ_HST)
#define SZ_FLG (NTEAMS*32*4)                  //       512
#define OFF_HFULL (OFF_FLG + SZ_FLG + 2048)
#define SZ_HFULL ((size_t)T_STEPS*NB*HID*2)   // 67,108,864
#define WS_NEED (OFF_HFULL + SZ_HFULL)

// ---------------------------------------------------------------------------
// prep2: f32->f16 weight conversion; zero hstate + flags WITH sc0 sc1 stores
// (the persistent kernel reads them via cache-bypass loads).
// ---------------------------------------------------------------------------
__global__ __launch_bounds__(256) void prep2_kernel(
    const float* __restrict__ W_ih, const float* __restrict__ W_hh,
    const float* __restrict__ fc_W, char* __restrict__ ws){
  _Float16* whhk = (_Float16*)(ws + OFF_WHHK);
  _Float16* wihk = (_Float16*)(ws + OFF_WIHK);
  _Float16* fck  = (_Float16*)(ws + OFF_FCK);
  u32* hz        = (u32*)(ws + OFF_HST);
  u32* flg       = (u32*)(ws + OFF_FLG);
  long idx = (long)blockIdx.x*256 + threadIdx.x;
  const long N1 = (long)G3*HID, N2 = (long)G3*KIN, N3 = (long)MST*HID;
  const long N4 = SZ_HST/4, N5 = SZ_FLG/4;
  if (idx < N1) whhk[idx] = (_Float16)W_hh[idx];
  else if (idx < N1+N2) wihk[idx-N1] = (_Float16)W_ih[idx-N1];
  else if (idx < N1+N2+N3) fck[idx-N1-N2] = (_Float16)fc_W[idx-N1-N2];
  else if (idx < N1+N2+N3+N4) { u32* p = hz + (idx-N1-N2-N3); u32 z = 0; STDW_SC(p, z); }
  else if (idx < N1+N2+N3+N4+N5) { u32* p = flg + (idx-N1-N2-N3-N4); u32 z = 0; STDW_SC(p, z); }
}

// ---------------------------------------------------------------------------
// X_prior: one WG (1 wave) per batch; F row-resident in VGPRs.
// Writes X_prior into d_out (fc kernel later adds dX in place).
// ---------------------------------------------------------------------------
__global__ __launch_bounds__(64) void xprior_kernel(
    const float* __restrict__ F, const float* __restrict__ x0,
    float* __restrict__ out){
  int b = blockIdx.x, i = threadIdx.x;
  __shared__ float xb[2][64];
  float f[64];
  #pragma unroll
  for (int j=0;j<64;j++) f[j] = F[i*64+j];
  xb[0][i] = x0[b*64+i];
  __syncthreads();
  float* o = out + (size_t)b*1024*64;
  for (int t=0;t<1024;t++){
    int cur = t & 1;
    float a0=0.f,a1=0.f,a2=0.f,a3=0.f;
    #pragma unroll
    for (int j=0;j<64;j+=4){
      a0 = fmaf(f[j+0], xb[cur][j+0], a0);
      a1 = fmaf(f[j+1], xb[cur][j+1], a1);
      a2 = fmaf(f[j+2], xb[cur][j+2], a2);
      a3 = fmaf(f[j+3], xb[cur][j+3], a3);
    }
    float a = (a0+a1)+(a2+a3);
    o[t*64+i] = a;
    xb[cur^1][i] = a;
    __syncthreads();
  }
}

// ---------------------------------------------------------------------------
// Persistent GRU v2: 64 WGs x 128 thr (2 independent waves; NO syncthreads,
// NO LDS). Team g = blk>>4 handles batches [g*16,(g+1)*16). Member m = blk&15
// owns j in [m*32,(m+1)*32); wave wv owns the 16-j subtile j0 = m*32+wv*16
// for ALL 3 gates -> gates compute entirely in registers.
// h exchange + flags via sc0 sc1 global ops (coherence point), ordering via
// vmcnt(0); one flag per wave, wave-local poll with __all.
// ---------------------------------------------------------------------------
__global__ __launch_bounds__(128, 1) void gru_pers2(
    const float* __restrict__ Y, const float* __restrict__ Xp,
    const float* __restrict__ b_ih, const float* __restrict__ b_hh,
    char* __restrict__ ws){
  const _Float16* whhk = (const _Float16*)(ws + OFF_WHHK);
  const _Float16* wihk = (const _Float16*)(ws + OFF_WIHK);
  _Float16* hstate     = (_Float16*)(ws + OFF_HST);
  u32* flags           = (u32*)(ws + OFF_FLG);
  _Float16* h_full     = (_Float16*)(ws + OFF_HFULL);

  const int blk = blockIdx.x;
  const int g = blk >> 4;          // team 0..3
  const int m = blk & 15;          // member 0..15
  const int tid = threadIdx.x;
  const int wv = tid >> 6;         // wave 0..1
  const int lane = tid & 63;
  const int lr = lane & 15, lk = lane >> 4;

  const int j0 = m*32 + wv*16;
  const int j  = j0 + lr;          // lane's output column (n)

  // Persistent B fragments: 60 x half8 = 240 VGPRs (full unroll -> registers)
  half8 Br[16], Bz[16], Bn[16], BrX[4], BzX[4], BnX[4];
  #pragma unroll
  for (int c=0;c<16;c++){
    Br[c] = *(const half8*)(whhk + ((size_t)(       j)*HID) + c*32 + lk*8);
    Bz[c] = *(const half8*)(whhk + ((size_t)(512  + j)*HID) + c*32 + lk*8);
    Bn[c] = *(const half8*)(whhk + ((size_t)(1024 + j)*HID) + c*32 + lk*8);
  }
  #pragma unroll
  for (int c=0;c<4;c++){
    BrX[c] = *(const half8*)(wihk + ((size_t)(       j)*KIN) + c*32 + lk*8);
    BzX[c] = *(const half8*)(wihk + ((size_t)(512  + j)*KIN) + c*32 + lk*8);
    BnX[c] = *(const half8*)(wihk + ((size_t)(1024 + j)*KIN) + c*32 + lk*8);
  }

  const float bR  = b_ih[j]      + b_hh[j];
  const float bZ  = b_ih[512+j]  + b_hh[512+j];
  const float bNX = b_ih[1024+j];
  const float bNH = b_hh[1024+j];

  // A-side input rows: lane lr = batch within team
  const float* Yb  = Y  + ((size_t)(g*16 + lr))*T_STEPS*NOBS;
  const float* Xpb = Xp + ((size_t)(g*16 + lr))*T_STEPS*MST;

  _Float16* hsg = hstate + (size_t)g*(2*16*HID);
  u32* flg = flags + g*32;
  u32* myflag   = flg + (m*2 + wv);
  u32* pollflag = flg + (lane & 31);

  float hold[4] = {0.f, 0.f, 0.f, 0.f};

  for (int t=0; t<T_STEPS; t++){
    // 1) prefetch inputs for step t (plain cached loads; consumed post-poll)
    const float* ysrc = Yb  + (size_t)t*NOBS;
    const float* xsrc = Xpb + (size_t)t*MST;
    float4 y0 = *(const float4*)(ysrc + lk*8);
    float4 y1 = *(const float4*)(ysrc + lk*8 + 4);
    float4 y2 = *(const float4*)(ysrc + 32 + lk*8);
    float4 y3 = *(const float4*)(ysrc + 32 + lk*8 + 4);
    float4 x0 = *(const float4*)(xsrc + lk*8);
    float4 x1 = *(const float4*)(xsrc + lk*8 + 4);
    float4 x2 = *(const float4*)(xsrc + 32 + lk*8);
    float4 x3 = *(const float4*)(xsrc + 32 + lk*8 + 4);

    // 2) wave-local poll: all 32 team flags >= t  (t=0 passes trivially)
    {
      u32 v;
      for(;;){
        asm volatile("global_load_dword %0, %1, off sc0 sc1\n\ts_waitcnt vmcnt(0)"
                     : "=v"(v) : "v"(pollflag) : "memory");
        if (__all((int)(v >= (u32)t))) break;
        __builtin_amdgcn_s_sleep(1);
      }
    }

    // 3) issue h A-fragment loads (cache-bypass)
    const _Float16* hb = hsg + (t&1)*(16*HID) + lr*HID + lk*8;
    uint4 ah[16];
    LDX4_SC(ah[ 0], hb,   0); LDX4_SC(ah[ 1], hb,  64);
    LDX4_SC(ah[ 2], hb, 128); LDX4_SC(ah[ 3], hb, 192);
    LDX4_SC(ah[ 4], hb, 256); LDX4_SC(ah[ 5], hb, 320);
    LDX4_SC(ah[ 6], hb, 384); LDX4_SC(ah[ 7], hb, 448);
    LDX4_SC(ah[ 8], hb, 512); LDX4_SC(ah[ 9], hb, 576);
    LDX4_SC(ah[10], hb, 640); LDX4_SC(ah[11], hb, 704);
    LDX4_SC(ah[12], hb, 768); LDX4_SC(ah[13], hb, 832);
    LDX4_SC(ah[14], hb, 896); LDX4_SC(ah[15], hb, 960);

    // 4) x-projection MFMAs overlap the h-load latency
    f32x4 aR={0,0,0,0}, aZ={0,0,0,0}, aNH={0,0,0,0}, aNX={0,0,0,0};
    {
      half8 Ax0 = pack8(y0,y1), Ax1 = pack8(y2,y3);
      half8 Ax2 = pack8(x0,x1), Ax3 = pack8(x2,x3);
      aR  = __builtin_amdgcn_mfma_f32_16x16x32_f16(Ax0, BrX[0], aR, 0,0,0);
      aZ  = __builtin_amdgcn_mfma_f32_16x16x32_f16(Ax0, BzX[0], aZ, 0,0,0);
      aNX = __builtin_amdgcn_mfma_f32_16x16x32_f16(Ax0, BnX[0], aNX,0,0,0);
      aR  = __builtin_amdgcn_mfma_f32_16x16x32_f16(Ax1, BrX[1], aR, 0,0,0);
      aZ  = __builtin_amdgcn_mfma_f32_16x16x32_f16(Ax1, BzX[1], aZ, 0,0,0);
      aNX = __builtin_amdgcn_mfma_f32_16x16x32_f16(Ax1, BnX[1], aNX,0,0,0);
      aR  = __builtin_amdgcn_mfma_f32_16x16x32_f16(Ax2, BrX[2], aR, 0,0,0);
      aZ  = __builtin_amdgcn_mfma_f32_16x16x32_f16(Ax2, BzX[2], aZ, 0,0,0);
      aNX = __builtin_amdgcn_mfma_f32_16x16x32_f16(Ax2, BnX[2], aNX,0,0,0);
      aR  = __builtin_amdgcn_mfma_f32_16x16x32_f16(Ax3, BrX[3], aR, 0,0,0);
      aZ  = __builtin_amdgcn_mfma_f32_16x16x32_f16(Ax3, BzX[3], aZ, 0,0,0);
      aNX = __builtin_amdgcn_mfma_f32_16x16x32_f16(Ax3, BnX[3], aNX,0,0,0);
    }

    // 5) drain h loads; sched_barrier stops MFMA hoisting past the waitcnt
    WAIT_VM0();
    __builtin_amdgcn_sched_barrier(0);

    // 6) hh MFMAs
    #pragma unroll
    for (int c=0;c<16;c++){
      U128 u; u.u = ah[c];
      half8 A = u.h;
      aR  = __builtin_amdgcn_mfma_f32_16x16x32_f16(A, Br[c], aR, 0,0,0);
      aZ  = __builtin_amdgcn_mfma_f32_16x16x32_f16(A, Bz[c], aZ, 0,0,0);
      aNH = __builtin_amdgcn_mfma_f32_16x16x32_f16(A, Bn[c], aNH,0,0,0);
    }

    // 7) gates fully in registers: lane owns (batch=lk*4+r, col j)
    float hn[4];
    #pragma unroll
    for (int r=0;r<4;r++){
      float cr = aR[r]  + bR;
      float cz = aZ[r]  + bZ;
      float cx = aNX[r] + bNX;
      float ch = aNH[r] + bNH;
      float rg = sigm(cr);
      float zg = sigm(cz);
      float ng = tanhf(cx + rg*ch);
      hn[r] = (1.f - zg)*ng + zg*hold[r];
      hold[r] = hn[r];
    }

    // 8) publish h_{t+1}: 4 sc0sc1 shorts -> vmcnt(0) -> flag store
    {
      _Float16* hw = hsg + ((t+1)&1)*(16*HID) + (size_t)(lk*4)*HID + j;
      u32 q0 = (u32)f16b(hn[0]);
      u32 q1 = (u32)f16b(hn[1]);
      u32 q2 = (u32)f16b(hn[2]);
      u32 q3 = (u32)f16b(hn[3]);
      STSH_SC(hw,    0, q0);
      STSH_SC(hw, 1024, q1);
      STSH_SC(hw, 2048, q2);
      STSH_SC(hw, 3072, q3);
      WAIT_VM0();
      if (lane == 0){
        u32 tv = (u32)(t+1);
        STDW_SC(myflag, tv);
      }
    }

    // 9) h_full for the deferred fc pass (plain stores, off critical path)
    {
      _Float16* hf = h_full + ((size_t)t*NB + g*16 + lk*4)*HID + j;
      hf[0]       = (_Float16)hn[0];
      hf[HID]     = (_Float16)hn[1];
      hf[2*HID]   = (_Float16)hn[2];
      hf[3*HID]   = (_Float16)hn[3];
    }
  }
}

// ---------------------------------------------------------------------------
// Deferred fc: out = X_prior(d_out) + h_full @ fcW^T + fc_b. MFMA, parallel.
// ---------------------------------------------------------------------------
__global__ __launch_bounds__(256) void fc_kernel(
    const float* __restrict__ fc_b, const char* __restrict__ ws,
    float* __restrict__ out){
  const _Float16* fck    = (const _Float16*)(ws + OFF_FCK);
  const _Float16* h_full = (const _Float16*)(ws + OFF_HFULL);
  int blk = blockIdx.x;
  int b  = blk >> 5;
  int t0 = (blk & 31) * 32;
  int tid = threadIdx.x, wv = tid >> 6, lane = tid & 63;
  int lr = lane & 15, lk = lane >> 4;
  int n = wv*16 + lr;
  half8 Bf[16];
  #pragma unroll
  for (int c=0;c<16;c++)
    Bf[c] = *(const half8*)(fck + (size_t)n*HID + c*32 + lk*8);
  float bias = fc_b[n];
  #pragma unroll
  for (int mt=0;mt<2;mt++){
    f32x4 C = {0.f,0.f,0.f,0.f};
    #pragma unroll
    for (int c=0;c<16;c++){
      half8 A = *(const half8*)(h_full + ((size_t)(t0+mt*16+lr)*NB + b)*HID + c*32 + lk*8);
      C = __builtin_amdgcn_mfma_f32_16x16x32_f16(A, Bf[c], C, 0,0,0);
    }
    #pragma unroll
    for (int r=0;r<4;r++){
      int trow = t0 + mt*16 + lk*4 + r;
      size_t o = ((size_t)b*T_STEPS + trow)*MST + n;
      out[o] = out[o] + bias + C[r];
    }
  }
}

// ===========================================================================
// Fallback path (round-1 kernels) — used only if ws_size < WS_NEED.
// ===========================================================================
#define NHH (3*128*512)
#define NIH (3*32*512)
#define NFC (8*16*64)

__global__ __launch_bounds__(256) void prep_kernel(
    const float* __restrict__ W_ih, const float* __restrict__ W_hh,
    const float* __restrict__ fc_W, uint2* __restrict__ whh_p,
    uint2* __restrict__ wih_p, uint2* __restrict__ wfc_p){
  int idx = blockIdx.x*256 + threadIdx.x;
  if (idx < NHH){
    int g = idx >> 16, rem = idx & 65535, k4 = rem >> 9, jj = rem & 511;
    const float* src = W_hh + (g*512 + jj)*512 + k4*4;
    whh_p[idx] = make_uint2(packh2(src[0],src[1]), packh2(src[2],src[3]));
  } else if (idx < NHH + NIH){
    int t = idx - NHH;
    int g = t >> 14, rem = t & 16383, k4 = rem >> 9, jj = rem & 511;
    const float* src = W_ih + (g*512 + jj)*128 + k4*4;
    wih_p[t] = make_uint2(packh2(src[0],src[1]), packh2(src[2],src[3]));
  } else {
    int t = idx - NHH - NIH;
    int ss = t >> 10, rem = t & 1023, k4 = rem >> 6, i = rem & 63;
    const float* src = fc_W + i*512 + ss*64 + k4*4;
    wfc_p[t] = make_uint2(packh2(src[0],src[1]), packh2(src[2],src[3]));
  }
}

__global__ __launch_bounds__(512) void gru_kernel(
    const float* __restrict__ Y, const float* __restrict__ b_ih,
    const float* __restrict__ b_hh, const float* __restrict__ fc_b,
    const uint2* __restrict__ WIH, const uint2* __restrict__ WHH,
    const uint2* __restrict__ WFC, float* __restrict__ out){
  int b = blockIdx.x, j = threadIdx.x;
  int ss = j >> 6, ii = j & 63;
  __shared__ u32 inp2[64];
  __shared__ float xp_lds[64];
  __shared__ u32 hbuf2[256];
  __shared__ float fcred[8][64];
  float br  = b_ih[j]      + b_hh[j];
  float bz  = b_ih[512+j]  + b_hh[512+j];
  float bxn = b_ih[1024+j];
  float bhn = b_hh[1024+j];
  float fb  = (j<64)? fc_b[j] : 0.f;
  float hreg = 0.f;
  if (j < 256) hbuf2[j] = 0u;
  const float* yb = Y   + (size_t)b*1024*64;
  float*       ob = out + (size_t)b*1024*64;
  for (int t=0;t<1024;t++){
    const float* yrow = yb + t*64;
    float*       orow = ob + t*64;
    if (j < 64){
      xp_lds[j] = orow[j];
      if (j < 32){
        float2 v = *(const float2*)(yrow + 2*j);
        inp2[j] = packh2(v.x, v.y);
      } else {
        float2 v = *(const float2*)(orow + 2*(j-32));
        inp2[j] = packh2(v.x, v.y);
      }
    }
    __syncthreads();
    float sr=br, sz=bz, sxn=bxn, shn=bhn;
    #pragma unroll 8
    for (int m=0;m<32;m++){
      uint2 wr = WIH[(m   )*512 + j];
      uint2 wz = WIH[(32+m)*512 + j];
      uint2 wn = WIH[(64+m)*512 + j];
      u32 x0 = inp2[2*m], x1 = inp2[2*m+1];
      sr  = dot2f(wr.x,x0,sr );  sr  = dot2f(wr.y,x1,sr );
      sz  = dot2f(wz.x,x0,sz );  sz  = dot2f(wz.y,x1,sz );
      sxn = dot2f(wn.x,x0,sxn);  sxn = dot2f(wn.y,x1,sxn);
    }
    #pragma unroll 8
    for (int m=0;m<128;m++){
      uint2 wr = WHH[(m     )*512 + j];
      uint2 wz = WHH[(128+m)*512 + j];
      uint2 wn = WHH[(256+m)*512 + j];
      u32 h0 = hbuf2[2*m], h1 = hbuf2[2*m+1];
      sr  = dot2f(wr.x,h0,sr );  sr  = dot2f(wr.y,h1,sr );
      sz  = dot2f(wz.x,h0,sz );  sz  = dot2f(wz.y,h1,sz );
      shn = dot2f(wn.x,h0,shn);  shn = dot2f(wn.y,h1,shn);
    }
    float r  = sigm(sr);
    float zg = sigm(sz);
    float ng = tanhf(sxn + r*shn);
    float hnew = (1.f - zg)*ng + zg*hreg;
    hreg = hnew;
    __syncthreads();
    ((u16*)hbuf2)[j] = f16b(hnew);
    __syncthreads();
    float p = 0.f;
    #pragma unroll
    for (int k4=0;k4<16;k4++){
      uint2 w2 = WFC[(ss*16 + k4)*64 + ii];
      u32 h0 = hbuf2[ss*32 + 2*k4], h1 = hbuf2[ss*32 + 2*k4 + 1];
      p = dot2f(w2.x,h0,p);  p = dot2f(w2.y,h1,p);
    }
    fcred[ss][ii] = p;
    __syncthreads();
    if (j < 64){
      float dx = fb + xp_lds[j];
      #pragma unroll
      for (int q=0;q<8;q++) dx += fcred[q][j];
      orow[j] = dx;
    }
  }
}

extern "C" void kernel_launch(void* const* d_in, const int* in_sizes, int n_in,
                              void* d_out, int out_size, void* d_ws, size_t ws_size,
                              hipStream_t stream){
  (void)in_sizes; (void)n_in; (void)out_size;
  const float* Y   = (const float*)d_in[0];
  const float* x0  = (const float*)d_in[1];
  const float* F   = (const float*)d_in[2];
  const float* Wih = (const float*)d_in[3];
  const float* Whh = (const float*)d_in[4];
  const float* bih = (const float*)d_in[5];
  const float* bhh = (const float*)d_in[6];
  const float* fcW = (const float*)d_in[7];
  const float* fcb = (const float*)d_in[8];
  float* out = (float*)d_out;

  if (ws_size >= (size_t)WS_NEED){
    char* ws = (char*)d_ws;
    prep2_kernel <<<4097, 256, 0, stream>>>(Wih, Whh, fcW, ws);
    xprior_kernel<<<  64,  64, 0, stream>>>(F, x0, out);
    gru_pers2    <<<  64, 128, 0, stream>>>(Y, out, bih, bhh, ws);
    fc_kernel    <<<2048, 256, 0, stream>>>(fcb, ws, out);
  } else {
    uint2* whh_p = (uint2*)d_ws;
    uint2* wih_p = (uint2*)((char*)d_ws + 1572864);
    uint2* wfc_p = (uint2*)((char*)d_ws + 1966080);
    prep_kernel  <<<992, 256, 0, stream>>>(Wih, Whh, fcW, whh_p, wih_p, wfc_p);
    xprior_kernel<<< 64,  64, 0, stream>>>(F, x0, out);
    gru_kernel   <<< 64, 512, 0, stream>>>(Y, bih, bhh, fcb, wih_p, whh_p, wfc_p, out);
  }
}

// Round 4
// 3269.902 us; speedup vs baseline: 8.6269x; 1.5434x over previous
//
#include <hip/hip_runtime.h>

typedef unsigned int u32;
typedef unsigned short u16;
typedef _Float16 half8 __attribute__((ext_vector_type(8)));
typedef float f32x4 __attribute__((ext_vector_type(4)));
typedef _Float16 h2t __attribute__((ext_vector_type(2)));

union H2U { u32 u; h2t h; u16 s[2]; };
union U128 { uint4 u; half8 h; };

#if defined(__has_builtin)
#if __has_builtin(__builtin_amdgcn_fdot2)
#define HAS_FDOT2 1
#endif
#endif

__device__ __forceinline__ float dot2f(u32 w, u32 x, float acc){
  H2U a, b; a.u = w; b.u = x;
#ifdef HAS_FDOT2
  return __builtin_amdgcn_fdot2(a.h, b.h, acc, false);
#else
  return acc + (float)a.h.x * (float)b.h.x + (float)a.h.y * (float)b.h.y;
#endif
}
__device__ __forceinline__ u32 packh2(float a, float b){
  H2U u; u.h.x = (_Float16)a; u.h.y = (_Float16)b; return u.u;
}
__device__ __forceinline__ u16 f16b(float x){
  union { _Float16 h; u16 u; } c; c.h = (_Float16)x; return c.u;
}
__device__ __forceinline__ float rcpf(float x){ return __builtin_amdgcn_rcpf(x); }
__device__ __forceinline__ float sigm(float x){ return rcpf(1.0f + __expf(-x)); }
__device__ __forceinline__ float sigm_slow(float x){ return 1.0f/(1.0f + __expf(-x)); }
__device__ __forceinline__ float tanh_f(float x){
  return fmaf(-2.0f, rcpf(1.0f + __expf(2.0f*x)), 1.0f);
}
__device__ __forceinline__ half8 pack8(float4 u, float4 v){
  half8 r;
  r[0]=(_Float16)u.x; r[1]=(_Float16)u.y; r[2]=(_Float16)u.z; r[3]=(_Float16)u.w;
  r[4]=(_Float16)v.x; r[5]=(_Float16)v.y; r[6]=(_Float16)v.z; r[7]=(_Float16)v.w;
  return r;
}

// Coherence-point access macros: no buffer_inv / buffer_wbl2 ever.
#define LDX4_SC(dst, base, off) \
  asm volatile("global_load_dwordx4 %0, %1, off offset:" #off " sc0 sc1" \
               : "=v"(dst) : "v"(base) : "memory")
#define STSH_SC(base, off, val) \
  asm volatile("global_store_short %0, %1, off offset:" #off " sc0 sc1" \
               :: "v"(base), "v"(val) : "memory")
#define STDW_SC(base, val) \
  asm volatile("global_store_dword %0, %1, off sc0 sc1" \
               :: "v"(base), "v"(val) : "memory")
#define WAIT_VM0() asm volatile("s_waitcnt vmcnt(0)" ::: "memory")

#define T_STEPS 1024
#define NB 64
#define HID 512
#define G3 1536
#define NOBS 64
#define MST 64
#define KIN 128

// ---- ws layout (persistent path), bytes ----
#define OFF_WHHK 0
#define SZ_WHHK (G3*HID*2)                    // 1,572,864
#define OFF_WIHK (OFF_WHHK + SZ_WHHK)
#define SZ_WIHK (G3*KIN*2)                    //   393,216
#define OFF_FCK (OFF_WIHK + SZ_WIHK)
#define SZ_FCK (MST*HID*2)                    //    65,536
#define OFF_FLG (OFF_FCK + SZ_FCK)
#define SZ_FLG (4*32*4)                       //       512 (4 teams x 32 WG flags)
#define OFF_HFULL (OFF_FLG + 4096)
#define SZ_HFULL ((size_t)T_STEPS*NB*HID*2)   // 67,108,864  (h_full[t] = h_{t+1} = outs[t])
#define WS_NEED (OFF_HFULL + SZ_HFULL)

// ---------------------------------------------------------------------------
// prep2: f32->f16 weight conversion; zero flags with sc0 sc1 stores (the
// persistent kernel polls them via cache-bypass loads).
// ---------------------------------------------------------------------------
__global__ __launch_bounds__(256) void prep2_kernel(
    const float* __restrict__ W_ih, const float* __restrict__ W_hh,
    const float* __restrict__ fc_W, char* __restrict__ ws){
  _Float16* whhk = (_Float16*)(ws + OFF_WHHK);
  _Float16* wihk = (_Float16*)(ws + OFF_WIHK);
  _Float16* fck  = (_Float16*)(ws + OFF_FCK);
  u32* flg       = (u32*)(ws + OFF_FLG);
  long idx = (long)blockIdx.x*256 + threadIdx.x;
  const long N1 = (long)G3*HID, N2 = (long)G3*KIN, N3 = (long)MST*HID;
  const long N4 = SZ_FLG/4;
  if (idx < N1) whhk[idx] = (_Float16)W_hh[idx];
  else if (idx < N1+N2) wihk[idx-N1] = (_Float16)W_ih[idx-N1];
  else if (idx < N1+N2+N3) fck[idx-N1-N2] = (_Float16)fc_W[idx-N1-N2];
  else if (idx < N1+N2+N3+N4) { u32* p = flg + (idx-N1-N2-N3); u32 z = 0; STDW_SC(p, z); }
}

// ---------------------------------------------------------------------------
// X_prior: one WG (1 wave) per batch; F row-resident in VGPRs.
// Writes X_prior into d_out (fc kernel later adds dX in place).
// ---------------------------------------------------------------------------
__global__ __launch_bounds__(64) void xprior_kernel(
    const float* __restrict__ F, const float* __restrict__ x0,
    float* __restrict__ out){
  int b = blockIdx.x, i = threadIdx.x;
  __shared__ float xb[2][64];
  float f[64];
  #pragma unroll
  for (int j=0;j<64;j++) f[j] = F[i*64+j];
  xb[0][i] = x0[b*64+i];
  __syncthreads();
  float* o = out + (size_t)b*1024*64;
  for (int t=0;t<1024;t++){
    int cur = t & 1;
    float a0=0.f,a1=0.f,a2=0.f,a3=0.f;
    #pragma unroll
    for (int j=0;j<64;j+=4){
      a0 = fmaf(f[j+0], xb[cur][j+0], a0);
      a1 = fmaf(f[j+1], xb[cur][j+1], a1);
      a2 = fmaf(f[j+2], xb[cur][j+2], a2);
      a3 = fmaf(f[j+3], xb[cur][j+3], a3);
    }
    float a = (a0+a1)+(a2+a3);
    o[t*64+i] = a;
    xb[cur^1][i] = a;
    __syncthreads();
  }
}

// ---------------------------------------------------------------------------
// Persistent GRU v3 (K-split): 128 WGs x 128 thr. Team g = blk>>5 owns
// batches [g*16,(g+1)*16); WG m = blk&31 owns j-tile [m*16,(m+1)*16) for all
// 3 gates. Wave wv in {0,1} owns K-half wv*256 of W_hh (and half of W_ih):
// B-frags = 120 VGPR/wave -> guaranteed register-resident (~200 live total).
// Partials combined through LDS; wave0 computes gates and publishes h into
// h_full[t] with sc0 sc1 stores + per-WG flag. Consumers poll the 32 team
// flags then LDX4_SC h_full[t-1]. No hstate buffer, no h stores on the
// next-step drain path.
// ---------------------------------------------------------------------------
__global__ __launch_bounds__(128, 1) void gru_pers3(
    const float* __restrict__ Y, const float* __restrict__ Xp,
    const float* __restrict__ b_ih, const float* __restrict__ b_hh,
    char* __restrict__ ws){
  const _Float16* whhk = (const _Float16*)(ws + OFF_WHHK);
  const _Float16* wihk = (const _Float16*)(ws + OFF_WIHK);
  u32* flags           = (u32*)(ws + OFF_FLG);
  _Float16* h_full     = (_Float16*)(ws + OFF_HFULL);

  const int blk = blockIdx.x;
  const int g = blk >> 5;          // team 0..3
  const int m = blk & 31;          // j-tile 0..31
  const int tid = threadIdx.x;
  const int wv = tid >> 6;         // K-half 0..1
  const int lane = tid & 63;
  const int lr = lane & 15, lk = lane >> 4;
  const int j = m*16 + lr;         // output column (n)

  // Persistent B fragments: 30 x half8 = 120 VGPRs
  half8 BhR[8], BhZ[8], BhN[8], BxR[2], BxZ[2], BxN[2];
  #pragma unroll
  for (int c=0;c<8;c++){
    BhR[c] = *(const half8*)(whhk + ((size_t)(       j))*HID + wv*256 + c*32 + lk*8);
    BhZ[c] = *(const half8*)(whhk + ((size_t)(512  + j))*HID + wv*256 + c*32 + lk*8);
    BhN[c] = *(const half8*)(whhk + ((size_t)(1024 + j))*HID + wv*256 + c*32 + lk*8);
  }
  #pragma unroll
  for (int c=0;c<2;c++){
    BxR[c] = *(const half8*)(wihk + ((size_t)(       j))*KIN + wv*64 + c*32 + lk*8);
    BxZ[c] = *(const half8*)(wihk + ((size_t)(512  + j))*KIN + wv*64 + c*32 + lk*8);
    BxN[c] = *(const half8*)(wihk + ((size_t)(1024 + j))*KIN + wv*64 + c*32 + lk*8);
  }

  const float bR  = b_ih[j]      + b_hh[j];
  const float bZ  = b_ih[512+j]  + b_hh[512+j];
  const float bNX = b_ih[1024+j];
  const float bNH = b_hh[1024+j];

  // A-side: wave0 streams Y (k 0..63), wave1 streams Xp (k 64..127);
  // lane row lr = batch within team.
  const float* Arow = (wv==0 ? Y : Xp) + ((size_t)(g*16 + lr))*T_STEPS*64;

  u32* flg = flags + g*32;
  u32* myflag   = flg + m;
  u32* pollflag = flg + (lane & 31);

  float hold[4] = {0.f, 0.f, 0.f, 0.f};
  __shared__ f32x4 part[4][64];

  for (int t=0; t<T_STEPS; t++){
    // 1) prefetch this wave's input chunk (plain cached loads)
    const float* asrc = Arow + (size_t)t*64;
    float4 i0 = *(const float4*)(asrc + lk*8);
    float4 i1 = *(const float4*)(asrc + lk*8 + 4);
    float4 i2 = *(const float4*)(asrc + 32 + lk*8);
    float4 i3 = *(const float4*)(asrc + 32 + lk*8 + 4);

    // 2) poll: all 32 team flags >= t (skip at t=0)
    if (t > 0){
      u32 v;
      for(;;){
        asm volatile("global_load_dword %0, %1, off sc0 sc1\n\ts_waitcnt vmcnt(0)"
                     : "=v"(v) : "v"(pollflag) : "memory");
        if (__all((int)(v >= (u32)t))) break;
      }
    }

    // 3) h_t A-frag loads for this wave's K-half (cache-bypass)
    uint4 ah[8];
    if (t > 0){
      const _Float16* hb = h_full + ((size_t)(t-1)*NB + g*16 + lr)*HID + wv*256 + lk*8;
      LDX4_SC(ah[0], hb,   0); LDX4_SC(ah[1], hb,  64);
      LDX4_SC(ah[2], hb, 128); LDX4_SC(ah[3], hb, 192);
      LDX4_SC(ah[4], hb, 256); LDX4_SC(ah[5], hb, 320);
      LDX4_SC(ah[6], hb, 384); LDX4_SC(ah[7], hb, 448);
    }
    WAIT_VM0();
    __builtin_amdgcn_sched_barrier(0);

    // 4) MFMA partials for this K-half
    f32x4 aR={0,0,0,0}, aZ={0,0,0,0}, aNH={0,0,0,0}, aNX={0,0,0,0};
    {
      half8 A0 = pack8(i0,i1), A1 = pack8(i2,i3);
      aR  = __builtin_amdgcn_mfma_f32_16x16x32_f16(A0, BxR[0], aR, 0,0,0);
      aZ  = __builtin_amdgcn_mfma_f32_16x16x32_f16(A0, BxZ[0], aZ, 0,0,0);
      aNX = __builtin_amdgcn_mfma_f32_16x16x32_f16(A0, BxN[0], aNX,0,0,0);
      aR  = __builtin_amdgcn_mfma_f32_16x16x32_f16(A1, BxR[1], aR, 0,0,0);
      aZ  = __builtin_amdgcn_mfma_f32_16x16x32_f16(A1, BxZ[1], aZ, 0,0,0);
      aNX = __builtin_amdgcn_mfma_f32_16x16x32_f16(A1, BxN[1], aNX,0,0,0);
    }
    if (t > 0){
      #pragma unroll
      for (int c=0;c<8;c++){
        U128 u; u.u = ah[c];
        half8 A = u.h;
        aR  = __builtin_amdgcn_mfma_f32_16x16x32_f16(A, BhR[c], aR, 0,0,0);
        aZ  = __builtin_amdgcn_mfma_f32_16x16x32_f16(A, BhZ[c], aZ, 0,0,0);
        aNH = __builtin_amdgcn_mfma_f32_16x16x32_f16(A, BhN[c], aNH,0,0,0);
      }
    }

    // 5) cross-wave K-reduction via LDS. Safe across iterations: wave1 can
    // only reach step t+1's write after this WG's flag hits t+1, which
    // wave0 sets after reading the partials below.
    if (wv == 1){
      part[0][lane] = aR;  part[1][lane] = aZ;
      part[2][lane] = aNH; part[3][lane] = aNX;
    }
    __syncthreads();

    if (wv == 0){
      aR  += part[0][lane]; aZ  += part[1][lane];
      aNH += part[2][lane]; aNX += part[3][lane];
      // 6) gates in registers: lane owns (batch=lk*4+r, col j)
      float hn[4];
      #pragma unroll
      for (int r=0;r<4;r++){
        float rg = sigm(aR[r] + bR);
        float zg = sigm(aZ[r] + bZ);
        float ng = tanh_f(aNX[r] + bNX + rg*(aNH[r] + bNH));
        hn[r] = (1.f - zg)*ng + zg*hold[r];
        hold[r] = hn[r];
      }
      // 7) publish h_{t+1} into h_full[t]: sc stores -> ack -> flag
      _Float16* hw = h_full + ((size_t)t*NB + g*16 + lk*4)*HID + j;
      u32 q0 = (u32)f16b(hn[0]);
      u32 q1 = (u32)f16b(hn[1]);
      u32 q2 = (u32)f16b(hn[2]);
      u32 q3 = (u32)f16b(hn[3]);
      STSH_SC(hw,    0, q0);
      STSH_SC(hw, 1024, q1);
      STSH_SC(hw, 2048, q2);
      STSH_SC(hw, 3072, q3);
      WAIT_VM0();
      if (lane == 0){
        u32 tv = (u32)(t+1);
        STDW_SC(myflag, tv);
      }
    }
  }
}

// ---------------------------------------------------------------------------
// Deferred fc: out = X_prior(d_out) + h_full @ fcW^T + fc_b. MFMA, parallel.
// (h_full[t] = outs[t]; kernel-boundary acquire makes plain loads coherent.)
// ---------------------------------------------------------------------------
__global__ __launch_bounds__(256) void fc_kernel(
    const float* __restrict__ fc_b, const char* __restrict__ ws,
    float* __restrict__ out){
  const _Float16* fck    = (const _Float16*)(ws + OFF_FCK);
  const _Float16* h_full = (const _Float16*)(ws + OFF_HFULL);
  int blk = blockIdx.x;
  int b  = blk >> 5;
  int t0 = (blk & 31) * 32;
  int tid = threadIdx.x, wv = tid >> 6, lane = tid & 63;
  int lr = lane & 15, lk = lane >> 4;
  int n = wv*16 + lr;
  half8 Bf[16];
  #pragma unroll
  for (int c=0;c<16;c++)
    Bf[c] = *(const half8*)(fck + (size_t)n*HID + c*32 + lk*8);
  float bias = fc_b[n];
  #pragma unroll
  for (int mt=0;mt<2;mt++){
    f32x4 C = {0.f,0.f,0.f,0.f};
    #pragma unroll
    for (int c=0;c<16;c++){
      half8 A = *(const half8*)(h_full + ((size_t)(t0+mt*16+lr)*NB + b)*HID + c*32 + lk*8);
      C = __builtin_amdgcn_mfma_f32_16x16x32_f16(A, Bf[c], C, 0,0,0);
    }
    #pragma unroll
    for (int r=0;r<4;r++){
      int trow = t0 + mt*16 + lk*4 + r;
      size_t o = ((size_t)b*T_STEPS + trow)*MST + n;
      out[o] = out[o] + bias + C[r];
    }
  }
}

// ===========================================================================
// Fallback path (round-1 kernels) — used only if ws_size < WS_NEED.
// ===========================================================================
#define NHH (3*128*512)
#define NIH (3*32*512)
#define NFC (8*16*64)

__global__ __launch_bounds__(256) void prep_kernel(
    const float* __restrict__ W_ih, const float* __restrict__ W_hh,
    const float* __restrict__ fc_W, uint2* __restrict__ whh_p,
    uint2* __restrict__ wih_p, uint2* __restrict__ wfc_p){
  int idx = blockIdx.x*256 + threadIdx.x;
  if (idx < NHH){
    int g = idx >> 16, rem = idx & 65535, k4 = rem >> 9, jj = rem & 511;
    const float* src = W_hh + (g*512 + jj)*512 + k4*4;
    whh_p[idx] = make_uint2(packh2(src[0],src[1]), packh2(src[2],src[3]));
  } else if (idx < NHH + NIH){
    int t = idx - NHH;
    int g = t >> 14, rem = t & 16383, k4 = rem >> 9, jj = rem & 511;
    const float* src = W_ih + (g*512 + jj)*128 + k4*4;
    wih_p[t] = make_uint2(packh2(src[0],src[1]), packh2(src[2],src[3]));
  } else {
    int t = idx - NHH - NIH;
    int ss = t >> 10, rem = t & 1023, k4 = rem >> 6, i = rem & 63;
    const float* src = fc_W + i*512 + ss*64 + k4*4;
    wfc_p[t] = make_uint2(packh2(src[0],src[1]), packh2(src[2],src[3]));
  }
}

__global__ __launch_bounds__(512) void gru_kernel(
    const float* __restrict__ Y, const float* __restrict__ b_ih,
    const float* __restrict__ b_hh, const float* __restrict__ fc_b,
    const uint2* __restrict__ WIH, const uint2* __restrict__ WHH,
    const uint2* __restrict__ WFC, float* __restrict__ out){
  int b = blockIdx.x, j = threadIdx.x;
  int ss = j >> 6, ii = j & 63;
  __shared__ u32 inp2[64];
  __shared__ float xp_lds[64];
  __shared__ u32 hbuf2[256];
  __shared__ float fcred[8][64];
  float br  = b_ih[j]      + b_hh[j];
  float bz  = b_ih[512+j]  + b_hh[512+j];
  float bxn = b_ih[1024+j];
  float bhn = b_hh[1024+j];
  float fb  = (j<64)? fc_b[j] : 0.f;
  float hreg = 0.f;
  if (j < 256) hbuf2[j] = 0u;
  const float* yb = Y   + (size_t)b*1024*64;
  float*       ob = out + (size_t)b*1024*64;
  for (int t=0;t<1024;t++){
    const float* yrow = yb + t*64;
    float*       orow = ob + t*64;
    if (j < 64){
      xp_lds[j] = orow[j];
      if (j < 32){
        float2 v = *(const float2*)(yrow + 2*j);
        inp2[j] = packh2(v.x, v.y);
      } else {
        float2 v = *(const float2*)(orow + 2*(j-32));
        inp2[j] = packh2(v.x, v.y);
      }
    }
    __syncthreads();
    float sr=br, sz=bz, sxn=bxn, shn=bhn;
    #pragma unroll 8
    for (int m=0;m<32;m++){
      uint2 wr = WIH[(m   )*512 + j];
      uint2 wz = WIH[(32+m)*512 + j];
      uint2 wn = WIH[(64+m)*512 + j];
      u32 x0 = inp2[2*m], x1 = inp2[2*m+1];
      sr  = dot2f(wr.x,x0,sr );  sr  = dot2f(wr.y,x1,sr );
      sz  = dot2f(wz.x,x0,sz );  sz  = dot2f(wz.y,x1,sz );
      sxn = dot2f(wn.x,x0,sxn);  sxn = dot2f(wn.y,x1,sxn);
    }
    #pragma unroll 8
    for (int m=0;m<128;m++){
      uint2 wr = WHH[(m     )*512 + j];
      uint2 wz = WHH[(128+m)*512 + j];
      uint2 wn = WHH[(256+m)*512 + j];
      u32 h0 = hbuf2[2*m], h1 = hbuf2[2*m+1];
      sr  = dot2f(wr.x,h0,sr );  sr  = dot2f(wr.y,h1,sr );
      sz  = dot2f(wz.x,h0,sz );  sz  = dot2f(wz.y,h1,sz );
      shn = dot2f(wn.x,h0,shn);  shn = dot2f(wn.y,h1,shn);
    }
    float r  = sigm_slow(sr);
    float zg = sigm_slow(sz);
    float ng = tanhf(sxn + r*shn);
    float hnew = (1.f - zg)*ng + zg*hreg;
    hreg = hnew;
    __syncthreads();
    ((u16*)hbuf2)[j] = f16b(hnew);
    __syncthreads();
    float p = 0.f;
    #pragma unroll
    for (int k4=0;k4<16;k4++){
      uint2 w2 = WFC[(ss*16 + k4)*64 + ii];
      u32 h0 = hbuf2[ss*32 + 2*k4], h1 = hbuf2[ss*32 + 2*k4 + 1];
      p = dot2f(w2.x,h0,p);  p = dot2f(w2.y,h1,p);
    }
    fcred[ss][ii] = p;
    __syncthreads();
    if (j < 64){
      float dx = fb + xp_lds[j];
      #pragma unroll
      for (int q=0;q<8;q++) dx += fcred[q][j];
      orow[j] = dx;
    }
  }
}

extern "C" void kernel_launch(void* const* d_in, const int* in_sizes, int n_in,
                              void* d_out, int out_size, void* d_ws, size_t ws_size,
                              hipStream_t stream){
  (void)in_sizes; (void)n_in; (void)out_size;
  const float* Y   = (const float*)d_in[0];
  const float* x0  = (const float*)d_in[1];
  const float* F   = (const float*)d_in[2];
  const float* Wih = (const float*)d_in[3];
  const float* Whh = (const float*)d_in[4];
  const float* bih = (const float*)d_in[5];
  const float* bhh = (const float*)d_in[6];
  const float* fcW = (const float*)d_in[7];
  const float* fcb = (const float*)d_in[8];
  float* out = (float*)d_out;

  if (ws_size >= (size_t)WS_NEED){
    char* ws = (char*)d_ws;
    prep2_kernel <<<3969, 256, 0, stream>>>(Wih, Whh, fcW, ws);
    xprior_kernel<<<  64,  64, 0, stream>>>(F, x0, out);
    gru_pers3    <<< 128, 128, 0, stream>>>(Y, out, bih, bhh, ws);
    fc_kernel    <<<2048, 256, 0, stream>>>(fcb, ws, out);
  } else {
    uint2* whh_p = (uint2*)d_ws;
    uint2* wih_p = (uint2*)((char*)d_ws + 1572864);
    uint2* wfc_p = (uint2*)((char*)d_ws + 1966080);
    prep_kernel  <<<992, 256, 0, stream>>>(Wih, Whh, fcW, whh_p, wih_p, wfc_p);
    xprior_kernel<<< 64,  64, 0, stream>>>(F, x0, out);
    gru_kernel   <<< 64, 512, 0, stream>>>(Y, bih, bhh, fcb, wih_p, whh_p, wfc_p, out);
  }
}